// Round 1
// baseline (48.935 us; speedup 1.0000x reference)
//
#include <hip/hip_runtime.h>

// Problem constants (fixed by the reference)
#define N_ROWS 4096
#define D_DIM  1024
#define NCLS   10

// k_partialT geometry
#define NSLICE     4                       // 256 dims per slice
#define SLICE_W    (D_DIM / NSLICE)        // 256
#define CHUNK_ROWS 32
#define NCHUNK     (N_ROWS / CHUNK_ROWS)   // 128
#define NB3        512                     // k_main blocks

// ws float-layout offsets
#define OFF_MEAN 0                         // 10*1024 floats (class sums -> means)
#define OFF_CNT  (NCLS * D_DIM)            // 10240: 16 ints
#define OFF_PL   (OFF_CNT + 16)            // 10256: NB3 floats
#define OFF_PT   (OFF_PL + NB3)            // 10768: NCHUNK*10*1024 floats
#define DET_FLOATS (OFF_PT + NCHUNK * NCLS * D_DIM)
#define ATOMIC_FLOATS OFF_PT

// ---------------------------------------------------------------- class counts
__global__ void k_count(const int* __restrict__ tgt, int* __restrict__ cnt) {
    int i = blockIdx.x * blockDim.x + threadIdx.x;
    if (i < N_ROWS) atomicAdd(&cnt[tgt[i]], 1);   // integer atomics: deterministic
}

// ------------------------------------------- per-class column sums (partials)
// grid = NCHUNK * NSLICE blocks, 256 threads. Block (chunk, slice) sums
// fm_t[chunk rows, slice dims] into 10 per-class register accumulators
// (compile-time indices only -> stays in VGPRs).
__global__ void k_partialT(const float* __restrict__ fm_t,
                           const int* __restrict__ tgt,
                           float* __restrict__ partialT) {
    int chunk = blockIdx.x / NSLICE;
    int slice = blockIdx.x % NSLICE;
    int tid   = threadIdx.x;

    __shared__ int tl[CHUNK_ROWS];
    if (tid < CHUNK_ROWS) tl[tid] = tgt[chunk * CHUNK_ROWS + tid];
    __syncthreads();

    float acc[NCLS];
#pragma unroll
    for (int k = 0; k < NCLS; ++k) acc[k] = 0.f;

    int col = slice * SLICE_W + tid;
    const float* base = fm_t + (size_t)chunk * CHUNK_ROWS * D_DIM + col;
#pragma unroll 4
    for (int r = 0; r < CHUNK_ROWS; ++r) {
        float v = base[(size_t)r * D_DIM];
        int   c = tl[r];
#pragma unroll
        for (int k = 0; k < NCLS; ++k) acc[k] += (c == k) ? v : 0.f;
    }

    float* out = partialT + (size_t)chunk * NCLS * D_DIM + col;
#pragma unroll
    for (int k = 0; k < NCLS; ++k) out[k * D_DIM] = acc[k];
}

// atomic-float fallback (only if ws is too small for the deterministic path)
__global__ void k_partialT_atomic(const float* __restrict__ fm_t,
                                  const int* __restrict__ tgt,
                                  float* __restrict__ sumT) {
    int chunk = blockIdx.x / NSLICE;
    int slice = blockIdx.x % NSLICE;
    int tid   = threadIdx.x;

    __shared__ int tl[CHUNK_ROWS];
    if (tid < CHUNK_ROWS) tl[tid] = tgt[chunk * CHUNK_ROWS + tid];
    __syncthreads();

    float acc[NCLS];
#pragma unroll
    for (int k = 0; k < NCLS; ++k) acc[k] = 0.f;

    int col = slice * SLICE_W + tid;
    const float* base = fm_t + (size_t)chunk * CHUNK_ROWS * D_DIM + col;
    for (int r = 0; r < CHUNK_ROWS; ++r) {
        float v = base[(size_t)r * D_DIM];
        int   c = tl[r];
#pragma unroll
        for (int k = 0; k < NCLS; ++k) acc[k] += (c == k) ? v : 0.f;
    }
#pragma unroll
    for (int k = 0; k < NCLS; ++k) atomicAdd(&sumT[k * D_DIM + col], acc[k]);
}

// ---------------------------------------------- reduce partials -> class mean
__global__ void k_reduceT(const float* __restrict__ partialT,
                          const int* __restrict__ cnt,
                          float* __restrict__ meanT) {
    int cell = blockIdx.x * blockDim.x + threadIdx.x;   // 10240 cells
    if (cell >= NCLS * D_DIM) return;
    float s = 0.f;
#pragma unroll 8
    for (int k = 0; k < NCHUNK; ++k)
        s += partialT[(size_t)k * NCLS * D_DIM + cell];
    int c = cell / D_DIM;
    meanT[cell] = s / (float)cnt[c];   // cnt==0 -> NaN, but then never read
}

__global__ void k_divmean(float* __restrict__ meanT, const int* __restrict__ cnt) {
    int cell = blockIdx.x * blockDim.x + threadIdx.x;
    if (cell >= NCLS * D_DIM) return;
    meanT[cell] = meanT[cell] / (float)cnt[cell / D_DIM];
}

// ------------- fused main pass: sum(s^2) - 2*s.mean_t[c]  +  sum(t^2) -------
__global__ void k_main(const float* __restrict__ fm_s,
                       const float* __restrict__ fm_t,
                       const int* __restrict__ tgt,
                       const float* __restrict__ meanT,
                       float* __restrict__ partialLoss) {
    int tid = threadIdx.x;
    int bid = blockIdx.x;
    float acc = 0.f;

    const int ROWS_PER_BLK = N_ROWS / NB3;   // 8
#pragma unroll
    for (int r = 0; r < ROWS_PER_BLK; ++r) {
        int row = bid * ROWS_PER_BLK + r;
        int c   = tgt[row];
        const float4* s4 = (const float4*)(fm_s + (size_t)row * D_DIM);
        const float4* m4 = (const float4*)(meanT + (size_t)c * D_DIM);
        float4 sv = s4[tid];   // 256 threads * float4 = 1024 dims
        float4 mv = m4[tid];
        acc += sv.x * sv.x + sv.y * sv.y + sv.z * sv.z + sv.w * sv.w
             - 2.f * (sv.x * mv.x + sv.y * mv.y + sv.z * mv.z + sv.w * mv.w);
    }

    const float4* t4 = (const float4*)fm_t;
    const int TOT4 = N_ROWS * D_DIM / 4;     // 1M float4
    for (int i = bid * blockDim.x + tid; i < TOT4; i += NB3 * 256) {
        float4 tv = t4[i];
        acc += tv.x * tv.x + tv.y * tv.y + tv.z * tv.z + tv.w * tv.w;
    }

    __shared__ float red[256];
    red[tid] = acc;
    __syncthreads();
    for (int s = 128; s > 0; s >>= 1) {
        if (tid < s) red[tid] += red[tid + s];
        __syncthreads();
    }
    if (tid == 0) partialLoss[bid] = red[0];
}

// ------------------------------------------------------------- final reduce
__global__ void k_final(const float* __restrict__ partialLoss, float* __restrict__ out) {
    int tid = threadIdx.x;   // 256
    double acc = 0.0;
    for (int i = tid; i < NB3; i += 256) acc += (double)partialLoss[i];
    __shared__ double red[256];
    red[tid] = acc;
    __syncthreads();
    for (int s = 128; s > 0; s >>= 1) {
        if (tid < s) red[tid] += red[tid + s];
        __syncthreads();
    }
    if (tid == 0) out[0] = (float)(red[0] / (double)N_ROWS);
}

extern "C" void kernel_launch(void* const* d_in, const int* in_sizes, int n_in,
                              void* d_out, int out_size, void* d_ws, size_t ws_size,
                              hipStream_t stream) {
    const float* fm_s = (const float*)d_in[0];
    const float* fm_t = (const float*)d_in[1];
    const int*   tgt  = (const int*)d_in[2];
    // d_in[3] (fusion_true) unused: reference takes the fusion_true==0 branch.

    float* ws       = (float*)d_ws;
    float* meanT    = ws + OFF_MEAN;
    int*   cnt      = (int*)(ws + OFF_CNT);
    float* ploss    = ws + OFF_PL;
    float* partialT = ws + OFF_PT;
    float* outp     = (float*)d_out;

    // zero counts + class-sum area (covers both paths); rest is fully overwritten
    hipMemsetAsync(d_ws, 0, (size_t)ATOMIC_FLOATS * sizeof(float), stream);

    k_count<<<N_ROWS / 256, 256, 0, stream>>>(tgt, cnt);

    if (ws_size >= (size_t)DET_FLOATS * sizeof(float)) {
        k_partialT<<<NCHUNK * NSLICE, 256, 0, stream>>>(fm_t, tgt, partialT);
        k_reduceT<<<(NCLS * D_DIM) / 256, 256, 0, stream>>>(partialT, cnt, meanT);
    } else {
        k_partialT_atomic<<<NCHUNK * NSLICE, 256, 0, stream>>>(fm_t, tgt, meanT);
        k_divmean<<<(NCLS * D_DIM) / 256, 256, 0, stream>>>(meanT, cnt);
    }

    k_main<<<NB3, 256, 0, stream>>>(fm_s, fm_t, tgt, meanT, ploss);
    k_final<<<1, 256, 0, stream>>>(ploss, outp);
}

// Round 2
// 28.924 us; speedup vs baseline: 1.6919x; 1.6919x over previous
//
#include <hip/hip_runtime.h>

// Problem constants (fixed by the reference)
#define N_ROWS 4096
#define D_DIM  1024
#define NCLS   10

// k_partialT geometry: 64 chunks x 4 slices = 256 blocks (1 per CU)
#define NSLICE     4
#define SLICE_W    (D_DIM / NSLICE)        // 256 == blockDim
#define CHUNK_ROWS 64
#define NCHUNK     (N_ROWS / CHUNK_ROWS)   // 64
#define NB2        (NCHUNK * NSLICE)       // 256 blocks in k_partialT
#define NB3        512                     // k_main blocks

// ws float-layout offsets (no zero-init required on the deterministic path)
#define OFF_MEAN 0                          // 10*1024 floats: class means
#define OFF_PL   (NCLS * D_DIM)             // 10240: NB3 floats (k_main partials)
#define OFF_PT2  (OFF_PL + NB3)             // 10752: NB2 floats (sum t^2 partials)
#define OFF_PT   (OFF_PT2 + NB2)            // 11008: NCHUNK*10*1024 floats
#define DET_FLOATS (OFF_PT + NCHUNK * NCLS * D_DIM)   // ~666K floats (2.7 MB)
#define ATOMIC_FLOATS OFF_PT

// ---------------- pass 1 over fm_t: per-class column sums + sum(t^2) --------
// Block (chunk, slice): rows [chunk*64, chunk*64+64), cols [slice*256 + tid].
// Per-thread register accumulators, compile-time indexed (stay in VGPRs).
__global__ void k_partialT(const float* __restrict__ fm_t,
                           const int* __restrict__ tgt,
                           float* __restrict__ partialT,
                           float* __restrict__ pt2) {
    int chunk = blockIdx.x / NSLICE;
    int slice = blockIdx.x % NSLICE;
    int tid   = threadIdx.x;

    __shared__ int tl[CHUNK_ROWS];
    if (tid < CHUNK_ROWS) tl[tid] = tgt[chunk * CHUNK_ROWS + tid];
    __syncthreads();

    float acc[NCLS];
#pragma unroll
    for (int k = 0; k < NCLS; ++k) acc[k] = 0.f;
    float acc2 = 0.f;

    int col = slice * SLICE_W + tid;
    const float* base = fm_t + (size_t)chunk * CHUNK_ROWS * D_DIM + col;
#pragma unroll 4
    for (int r = 0; r < CHUNK_ROWS; ++r) {
        float v = base[(size_t)r * D_DIM];
        int   c = tl[r];
        acc2 += v * v;
#pragma unroll
        for (int k = 0; k < NCLS; ++k) acc[k] += (c == k) ? v : 0.f;
    }

    float* out = partialT + (size_t)chunk * NCLS * D_DIM + col;
#pragma unroll
    for (int k = 0; k < NCLS; ++k) out[k * D_DIM] = acc[k];

    __shared__ float red[256];
    red[tid] = acc2;
    __syncthreads();
    for (int s = 128; s > 0; s >>= 1) {
        if (tid < s) red[tid] += red[tid + s];
        __syncthreads();
    }
    if (tid == 0) pt2[blockIdx.x] = red[0];
}

// ------- reduce partials -> class mean; class counts built in-LDS here ------
__global__ void k_reduceT(const float* __restrict__ partialT,
                          const int* __restrict__ tgt,
                          float* __restrict__ meanT) {
    int tid = threadIdx.x;

    __shared__ int hist[NCLS];
    if (tid < NCLS) hist[tid] = 0;
    __syncthreads();
    for (int i = tid; i < N_ROWS; i += 256) atomicAdd(&hist[tgt[i]], 1);
    __syncthreads();

    int cell = blockIdx.x * 256 + tid;      // 10240 cells, 40 blocks
    if (cell >= NCLS * D_DIM) return;
    float s = 0.f;
#pragma unroll 8
    for (int k = 0; k < NCHUNK; ++k)
        s += partialT[(size_t)k * NCLS * D_DIM + cell];
    meanT[cell] = s / (float)hist[cell / D_DIM];
}

// ------------------------- atomic-float fallback path -----------------------
__global__ void k_zero(float* __restrict__ p, int n) {
    int i = blockIdx.x * blockDim.x + threadIdx.x;
    if (i < n) p[i] = 0.f;
}

__global__ void k_partialT_atomic(const float* __restrict__ fm_t,
                                  const int* __restrict__ tgt,
                                  float* __restrict__ sumT,
                                  float* __restrict__ pt2) {
    int chunk = blockIdx.x / NSLICE;
    int slice = blockIdx.x % NSLICE;
    int tid   = threadIdx.x;

    __shared__ int tl[CHUNK_ROWS];
    if (tid < CHUNK_ROWS) tl[tid] = tgt[chunk * CHUNK_ROWS + tid];
    __syncthreads();

    float acc[NCLS];
#pragma unroll
    for (int k = 0; k < NCLS; ++k) acc[k] = 0.f;
    float acc2 = 0.f;

    int col = slice * SLICE_W + tid;
    const float* base = fm_t + (size_t)chunk * CHUNK_ROWS * D_DIM + col;
    for (int r = 0; r < CHUNK_ROWS; ++r) {
        float v = base[(size_t)r * D_DIM];
        int   c = tl[r];
        acc2 += v * v;
#pragma unroll
        for (int k = 0; k < NCLS; ++k) acc[k] += (c == k) ? v : 0.f;
    }
#pragma unroll
    for (int k = 0; k < NCLS; ++k) atomicAdd(&sumT[k * D_DIM + col], acc[k]);

    __shared__ float red[256];
    red[tid] = acc2;
    __syncthreads();
    for (int s = 128; s > 0; s >>= 1) {
        if (tid < s) red[tid] += red[tid + s];
        __syncthreads();
    }
    if (tid == 0) pt2[blockIdx.x] = red[0];
}

__global__ void k_divmean(float* __restrict__ meanT, const int* __restrict__ tgt) {
    int tid = threadIdx.x;
    __shared__ int hist[NCLS];
    if (tid < NCLS) hist[tid] = 0;
    __syncthreads();
    for (int i = tid; i < N_ROWS; i += 256) atomicAdd(&hist[tgt[i]], 1);
    __syncthreads();
    int cell = blockIdx.x * 256 + tid;
    if (cell >= NCLS * D_DIM) return;
    meanT[cell] = meanT[cell] / (float)hist[cell / D_DIM];
}

// --------------- pass over fm_s: sum(s^2) - 2*s.mean_t[c] -------------------
__global__ void k_main(const float* __restrict__ fm_s,
                       const int* __restrict__ tgt,
                       const float* __restrict__ meanT,
                       float* __restrict__ partialLoss) {
    int tid = threadIdx.x;
    int bid = blockIdx.x;
    float acc = 0.f;

    const int ROWS_PER_BLK = N_ROWS / NB3;   // 8
#pragma unroll
    for (int r = 0; r < ROWS_PER_BLK; ++r) {
        int row = bid * ROWS_PER_BLK + r;
        int c   = tgt[row];
        const float4* s4 = (const float4*)(fm_s + (size_t)row * D_DIM);
        const float4* m4 = (const float4*)(meanT + (size_t)c * D_DIM);
        float4 sv = s4[tid];   // 256 threads * float4 = 1024 dims
        float4 mv = m4[tid];   // meanT is 40 KB -> L1/L2 hot
        acc += sv.x * sv.x + sv.y * sv.y + sv.z * sv.z + sv.w * sv.w
             - 2.f * (sv.x * mv.x + sv.y * mv.y + sv.z * mv.z + sv.w * mv.w);
    }

    __shared__ float red[256];
    red[tid] = acc;
    __syncthreads();
    for (int s = 128; s > 0; s >>= 1) {
        if (tid < s) red[tid] += red[tid + s];
        __syncthreads();
    }
    if (tid == 0) partialLoss[bid] = red[0];
}

// ------------------------------------------------------------- final reduce
__global__ void k_final(const float* __restrict__ partialLoss,
                        const float* __restrict__ pt2,
                        float* __restrict__ out) {
    int tid = threadIdx.x;   // 256
    double acc = 0.0;
    for (int i = tid; i < NB3; i += 256) acc += (double)partialLoss[i];
    acc += (double)pt2[tid];               // NB2 == 256
    __shared__ double red[256];
    red[tid] = acc;
    __syncthreads();
    for (int s = 128; s > 0; s >>= 1) {
        if (tid < s) red[tid] += red[tid + s];
        __syncthreads();
    }
    if (tid == 0) out[0] = (float)(red[0] / (double)N_ROWS);
}

extern "C" void kernel_launch(void* const* d_in, const int* in_sizes, int n_in,
                              void* d_out, int out_size, void* d_ws, size_t ws_size,
                              hipStream_t stream) {
    const float* fm_s = (const float*)d_in[0];
    const float* fm_t = (const float*)d_in[1];
    const int*   tgt  = (const int*)d_in[2];
    // d_in[3] (fusion_true) unused: reference takes the fusion_true==0 branch.

    float* ws       = (float*)d_ws;
    float* meanT    = ws + OFF_MEAN;
    float* ploss    = ws + OFF_PL;
    float* pt2      = ws + OFF_PT2;
    float* partialT = ws + OFF_PT;
    float* outp     = (float*)d_out;

    if (ws_size >= (size_t)DET_FLOATS * sizeof(float)) {
        // Deterministic path, no zero-init needed anywhere.
        k_partialT<<<NB2, 256, 0, stream>>>(fm_t, tgt, partialT, pt2);
        k_reduceT<<<(NCLS * D_DIM + 255) / 256, 256, 0, stream>>>(partialT, tgt, meanT);
    } else {
        k_zero<<<(NCLS * D_DIM + 255) / 256, 256, 0, stream>>>(meanT, NCLS * D_DIM);
        k_partialT_atomic<<<NB2, 256, 0, stream>>>(fm_t, tgt, meanT, pt2);
        k_divmean<<<(NCLS * D_DIM + 255) / 256, 256, 0, stream>>>(meanT, tgt);
    }

    k_main<<<NB3, 256, 0, stream>>>(fm_s, tgt, meanT, ploss);
    k_final<<<1, 256, 0, stream>>>(ploss, pt2, outp);
}